// Round 10
// baseline (287.721 us; speedup 1.0000x reference)
//
#include <hip/hip_runtime.h>
#include <hip/hip_bf16.h>

#define EMB 1024
#define SEQ 2048
#define ATT_SCALE 0.18033688011112042f  // 0.125 * log2(e)

typedef __bf16 bf16x8 __attribute__((ext_vector_type(8)));
typedef float f32x4 __attribute__((ext_vector_type(4)));
typedef float f32x16 __attribute__((ext_vector_type(16)));

__device__ __forceinline__ unsigned short f2bf(float f) {
    union { float f; unsigned int u; } v; v.f = f;
    unsigned int r = (v.u + 0x7FFFu + ((v.u >> 16) & 1u)) >> 16;
    return (unsigned short)r;
}

__device__ __forceinline__ void async_load16(const void* g, void* l) {
    __builtin_amdgcn_global_load_lds(
        (const __attribute__((address_space(1))) unsigned int*)g,
        (__attribute__((address_space(3))) unsigned int*)l, 16, 0, 0);
}

// ---------------- fused prep: X f32->bf16  +  Wqkv^T  +  Wproj^T ----------------
__global__ __launch_bounds__(256)
void prep(const float* __restrict__ X, unsigned short* __restrict__ Xb,
          const float* __restrict__ Wqkv, unsigned short* __restrict__ WqkvT,
          const float* __restrict__ Wproj, unsigned short* __restrict__ WprojT) {
    __shared__ float tile[32][33];
    const int id = blockIdx.x;
    const int tid = threadIdx.x;
    if (id < 4096) {
        const float* in;
        unsigned short* out;
        int bx, by, C;
        if (id < 3072) { in = Wqkv; out = WqkvT; C = 3072; bx = (id % 96) * 32; by = (id / 96) * 32; }
        else           { int t = id - 3072; in = Wproj; out = WprojT; C = 1024; bx = (t % 32) * 32; by = (t / 32) * 32; }
        int tx = tid & 31;
        int ty = tid >> 5;
        #pragma unroll
        for (int i = 0; i < 32; i += 8)
            tile[ty + i][tx] = in[(size_t)(by + ty + i) * C + bx + tx];
        __syncthreads();
        #pragma unroll
        for (int i = 0; i < 32; i += 8)
            out[(size_t)(bx + ty + i) * 1024 + by + tx] = f2bf(tile[tx][ty + i]);
    } else {
        const int n4 = (4 * 2048 * 1024) / 4;
        int i = (id - 4096) * 256 + tid;
        const int stride = 2048 * 256;
        const float4* inv = (const float4*)X;
        ushort4* outv = (ushort4*)Xb;
        for (; i < n4; i += stride) {
            float4 v = inv[i];
            ushort4 o;
            o.x = f2bf(v.x); o.y = f2bf(v.y); o.z = f2bf(v.z); o.w = f2bf(v.w);
            outv[i] = o;
        }
    }
}

// ---------------- bf16 MFMA GEMM, 32x32x16 shape: C[M,N] = A * Bt^T + bias ----------------
// R5/R8-proven single-buffer 2-barrier structure (plateau config).
// FUSE_VT pre-scales Q columns (col < EMB) by ATT_SCALE and writes V transposed.
#define BM 128
#define BN 128
#define BK 64

template<bool OUT_BF16, bool FUSE_VT, int NPER>
__global__ __launch_bounds__(256, 4)
void gemm_bf16(const unsigned short* __restrict__ A,
               const unsigned short* __restrict__ Bt,
               const float* __restrict__ bias,
               void* __restrict__ Cout,
               unsigned short* __restrict__ Vtout,
               int M, int N, int K) {
    __shared__ unsigned short As[BM * 64];
    __shared__ unsigned short Bs[BN * 64];
    const int tid = threadIdx.x;
    const int id = blockIdx.x;
    const int xcd = id & 7;
    const int loc = id >> 3;
    const int m0 = (loc / NPER) * BM;
    const int n0 = (xcd * NPER + (loc % NPER)) * BN;
    const int lane = tid & 63;
    const int wave = tid >> 6;
    const int wm = (wave & 1) * 64;
    const int wn = (wave >> 1) * 64;
    const int l31 = lane & 31;
    const int half = lane >> 5;
    const int r8 = lane >> 3;
    const int pc = lane & 7;

    const int srow = wave * 32 + r8;
    f32x16 acc[2][2] = {};

    for (int k0 = 0; k0 < K; k0 += BK) {
        __syncthreads();
        #pragma unroll
        for (int i = 0; i < 4; i++) {
            int r = srow + i * 8;
            int lc = pc ^ (r & 7);
            async_load16(&A[(size_t)(m0 + r) * K + k0 + lc * 8], &As[(wave * 32 + i * 8) * 64]);
            async_load16(&Bt[(size_t)(n0 + r) * K + k0 + lc * 8], &Bs[(wave * 32 + i * 8) * 64]);
        }
        __syncthreads();
        #pragma unroll
        for (int ks = 0; ks < 4; ks++) {
            const int lch = ks * 2 + half;
            bf16x8 af[2], bf[2];
            #pragma unroll
            for (int t = 0; t < 2; t++) {
                int ra = wm + t * 32 + l31;
                int rb = wn + t * 32 + l31;
                af[t] = *(const bf16x8*)&As[ra * 64 + (lch ^ (ra & 7)) * 8];
                bf[t] = *(const bf16x8*)&Bs[rb * 64 + (lch ^ (rb & 7)) * 8];
            }
            #pragma unroll
            for (int mt = 0; mt < 2; mt++)
                #pragma unroll
                for (int nt = 0; nt < 2; nt++)
                    acc[mt][nt] = __builtin_amdgcn_mfma_f32_32x32x16_bf16(
                        af[mt], bf[nt], acc[mt][nt], 0, 0, 0);
        }
    }
    #pragma unroll
    for (int mt = 0; mt < 2; mt++) {
        #pragma unroll
        for (int nt = 0; nt < 2; nt++) {
            int col = n0 + wn + nt * 32 + l31;
            float bv = bias[col];
            if (FUSE_VT && col >= 2 * EMB) {
                int dd = col - 2 * EMB;
                #pragma unroll
                for (int g = 0; g < 4; g++) {
                    int row0 = m0 + wm + mt * 32 + 8 * g + 4 * half;
                    int b = row0 >> 11;
                    int s = row0 & 2047;
                    ushort4 o;
                    o.x = f2bf(acc[mt][nt][4 * g + 0] + bv);
                    o.y = f2bf(acc[mt][nt][4 * g + 1] + bv);
                    o.z = f2bf(acc[mt][nt][4 * g + 2] + bv);
                    o.w = f2bf(acc[mt][nt][4 * g + 3] + bv);
                    *(ushort4*)&Vtout[((size_t)(b * 16) * 64 + dd) * SEQ + s] = o;
                }
            } else {
                const bool qscale = FUSE_VT && (col < EMB);
                #pragma unroll
                for (int reg = 0; reg < 16; reg++) {
                    int row = m0 + wm + mt * 32 + (reg & 3) + 8 * (reg >> 2) + 4 * half;
                    float val = acc[mt][nt][reg] + bv;
                    if (qscale) val *= ATT_SCALE;
                    if (OUT_BF16)
                        ((unsigned short*)Cout)[(size_t)row * N + col] = f2bf(val);
                    else
                        ((float*)Cout)[(size_t)row * N + col] = val;
                }
            }
        }
    }
}

// ---------------- MFMA flash attention, S^T, 2 waves x 64 q-rows ----------------
// All waves in a block share bh -> K/V LDS fragments are identical across
// waves. 2 waves x 2 q-sub-tiles each (instead of 4 waves x 1) halves per-CU
// LDS read traffic + bank conflicts: each kf/vf ds_read_b128 feeds TWO MFMAs.
// Grid stays 1024 blocks (4/CU) with the PROVEN magic-square decode.
// Fixed-max softmax; Q pre-scaled in QKV GEMM -> exp2f(st) directly.
// global_load_lds staging, pre-swizzled source + XOR-swizzled ds_read_b128.
// permlane32_swap P-exchange. Deferred lsum tree per sub-tile.
__global__ __launch_bounds__(128, 2)
void attention(const unsigned short* __restrict__ qkv,   // [8192][3072] bf16
               const unsigned short* __restrict__ vt,    // [64][64][2048] bf16
               unsigned short* __restrict__ outb) {      // [8192][1024] bf16
    __shared__ unsigned short smem[2 * 2 * 64 * 64];     // 2 buf x (K,V) x 64x64 = 32 KB
    const int tid = threadIdx.x;          // 0..127
    const int lane = tid & 63;
    const int wave = tid >> 6;            // 0..1
    const int l31 = lane & 31;
    const int half = lane >> 5;

    // magic-square balanced decode (proven): qt rows/cols each sum to 30
    const int id = blockIdx.x;
    const int m4 = ((id >> 8) << 2) | (id & 3);
    const int qt = (int)((0xF12C4A97865B3DE0ULL >> (m4 * 4)) & 15);
    const int bh = (id & 255) >> 2;
    const int b = bh >> 4;
    const int h = bh & 15;

    const int qb = qt * 128 + wave * 64;  // this wave's q-row base (64 rows)

    bf16x8 qf[2][4];
    #pragma unroll
    for (int u = 0; u < 2; u++)
        #pragma unroll
        for (int dt = 0; dt < 4; dt++)
            qf[u][dt] = *(const bf16x8*)&qkv[(size_t)(b * SEQ + qb + u * 32 + l31) * 3072
                                             + h * 64 + dt * 16 + half * 8];

    f32x16 o[2][2] = {};
    float tsum[2][8];
    #pragma unroll
    for (int u = 0; u < 2; u++)
        #pragma unroll
        for (int r = 0; r < 8; r++) tsum[u][r] = 0.f;

    const int nkb = 2 * qt + 2;
    const int qmax_w = qb + 63;

    const int row16 = tid >> 3;                     // 0..15 source row group
    const int chsw = ((tid & 7) ^ (row16 & 7)) * 8; // pre-swizzled source chunk

    // stage kb=0 into buffer 0 (8 loads/thread: 4 K + 4 V)
    #pragma unroll
    for (int i = 0; i < 4; i++) {
        int row = row16 + 16 * i;
        int lb = (wave * 8 + 16 * i) * 64;   // wave-uniform LDS dest base
        async_load16(&qkv[(size_t)(b * SEQ + row) * 3072 + EMB + h * 64 + chsw], &smem[lb]);
        async_load16(&vt[(size_t)(bh * 64 + row) * SEQ + chsw], &smem[4096 + lb]);
    }

    for (int kb = 0; kb < nkb; kb++) {
        unsigned short* Ks = smem + (kb & 1) * 8192;
        unsigned short* Vs = Ks + 4096;
        __syncthreads();   // drains loads for buf[kb&1]; guards buf[(kb+1)&1] reuse
        if (kb + 1 < nkb) {
            unsigned short* nb = smem + ((kb + 1) & 1) * 8192;
            #pragma unroll
            for (int i = 0; i < 4; i++) {
                int row = row16 + 16 * i;
                int lb = (wave * 8 + 16 * i) * 64;
                async_load16(&qkv[(size_t)(b * SEQ + (kb + 1) * 64 + row) * 3072 + EMB + h * 64 + chsw],
                             &nb[lb]);
                async_load16(&vt[(size_t)(bh * 64 + row) * SEQ + (kb + 1) * 64 + chsw],
                             &nb[4096 + lb]);
            }
        }
        if (kb * 64 > qmax_w) continue;

        // S^T = K Q^T : each kf read feeds BOTH q-sub-tiles
        f32x16 st[2][2] = {};
        __builtin_amdgcn_s_setprio(1);
        #pragma unroll
        for (int dt = 0; dt < 4; dt++) {
            #pragma unroll
            for (int ct = 0; ct < 2; ct++) {
                int kr = ct * 32 + l31;
                bf16x8 kf = *(const bf16x8*)&Ks[kr * 64 + ((dt * 2 + half) ^ (l31 & 7)) * 8];
                st[0][ct] = __builtin_amdgcn_mfma_f32_32x32x16_bf16(kf, qf[0][dt], st[0][ct], 0, 0, 0);
                st[1][ct] = __builtin_amdgcn_mfma_f32_32x32x16_bf16(kf, qf[1][dt], st[1][ct], 0, 0, 0);
            }
        }
        __builtin_amdgcn_s_setprio(0);

        // causal mask per sub-tile
        #pragma unroll
        for (int u = 0; u < 2; u++) {
            if (kb * 64 + 63 > qb + u * 32) {
                int qsu = qb + u * 32 + l31;
                #pragma unroll
                for (int ct = 0; ct < 2; ct++)
                    #pragma unroll
                    for (int r = 0; r < 16; r++) {
                        int cg = kb * 64 + ct * 32 + (r & 3) + 8 * (r >> 2) + 4 * half;
                        if (cg > qsu) st[u][ct][r] = -1e9f;
                    }
            }
        }

        // fixed-max softmax: P = exp2(st); masked -> 0. Sum deferred in-lane.
        unsigned int pk[2][2][8];
        #pragma unroll
        for (int u = 0; u < 2; u++) {
            #pragma unroll
            for (int r = 0; r < 16; r++) {
                st[u][0][r] = exp2f(st[u][0][r]);
                st[u][1][r] = exp2f(st[u][1][r]);
            }
            #pragma unroll
            for (int r = 0; r < 8; r++)
                tsum[u][r] += (st[u][0][r] + st[u][1][r]) + (st[u][0][r + 8] + st[u][1][r + 8]);
            #pragma unroll
            for (int t = 0; t < 2; t++)
                #pragma unroll
                for (int i = 0; i < 8; i++) {
                    __hip_bfloat162 pb = __float22bfloat162_rn(float2{st[u][t][2 * i], st[u][t][2 * i + 1]});
                    union { __hip_bfloat162 b; unsigned int u; } cv; cv.b = pb;
                    pk[u][t][i] = cv.u;
                }
        }

        // PV: each vf read feeds BOTH sub-tiles' MFMAs
        __builtin_amdgcn_s_setprio(1);
        #pragma unroll
        for (int kt = 0; kt < 4; kt++) {
            const int t = kt >> 1, e = kt & 1;
            union { uint4 u4; bf16x8 v; } pf[2];
            #pragma unroll
            for (int u = 0; u < 2; u++) {
                unsigned int a0 = pk[u][t][4 * e + 0], b0 = pk[u][t][4 * e + 2];
                unsigned int a1 = pk[u][t][4 * e + 1], b1 = pk[u][t][4 * e + 3];
                asm("v_permlane32_swap_b32 %0, %1" : "+v"(a0), "+v"(b0));
                asm("v_permlane32_swap_b32 %0, %1" : "+v"(a1), "+v"(b1));
                pf[u].u4.x = a0; pf[u].u4.y = a1; pf[u].u4.z = b0; pf[u].u4.w = b1;
            }
            #pragma unroll
            for (int dt = 0; dt < 2; dt++) {
                int vr = dt * 32 + l31;
                bf16x8 vf = *(const bf16x8*)&Vs[vr * 64 + ((kt * 2 + half) ^ (l31 & 7)) * 8];
                o[0][dt] = __builtin_amdgcn_mfma_f32_32x32x16_bf16(vf, pf[0].v, o[0][dt], 0, 0, 0);
                o[1][dt] = __builtin_amdgcn_mfma_f32_32x32x16_bf16(vf, pf[1].v, o[1][dt], 0, 0, 0);
            }
        }
        __builtin_amdgcn_s_setprio(0);
    }

    // epilogue: per-sub-tile lsum tree; O^T -> LDS [q][d] -> coalesced store
    __syncthreads();
    #pragma unroll
    for (int u = 0; u < 2; u++) {
        #pragma unroll
        for (int s = 4; s > 0; s >>= 1)
            #pragma unroll
            for (int r = 0; r < s; r++) tsum[u][r] += tsum[u][r + s];
        float lt = tsum[u][0] + __shfl_xor(tsum[u][0], 32, 64);
        float inv = 1.0f / lt;
        #pragma unroll
        for (int dt = 0; dt < 2; dt++)
            #pragma unroll
            for (int r = 0; r < 16; r++) {
                int d = dt * 32 + (r & 3) + 8 * (r >> 2) + 4 * half;
                smem[(wave * 64 + u * 32 + l31) * 72 + d] = f2bf(o[u][dt][r] * inv);
            }
    }
    __syncthreads();
    #pragma unroll
    for (int i = 0; i < 8; i++) {
        int c = tid + 128 * i;
        int row = c >> 3;
        int ch = (c & 7) * 8;
        uint4 v = *(const uint4*)&smem[row * 72 + ch];
        *(uint4*)&outb[(size_t)(b * SEQ + qt * 128 + row) * EMB + h * 64 + ch] = v;
    }
}

extern "C" void kernel_launch(void* const* d_in, const int* in_sizes, int n_in,
                              void* d_out, int out_size, void* d_ws, size_t ws_size,
                              hipStream_t stream) {
    const float* X     = (const float*)d_in[0];
    const float* Wqkv  = (const float*)d_in[1];
    const float* bqkv  = (const float*)d_in[2];
    const float* Wproj = (const float*)d_in[3];
    const float* bproj = (const float*)d_in[4];
    float* out = (float*)d_out;

    char* ws = (char*)d_ws;
    unsigned short* Xb     = (unsigned short*)(ws);                // 16,777,216 B
    unsigned short* WqkvT  = (unsigned short*)(ws + 16777216);     //  6,291,456 B
    unsigned short* WprojT = (unsigned short*)(ws + 23068672);     //  2,097,152 B
    unsigned short* qkvb   = (unsigned short*)(ws + 25165824);     // 50,331,648 B
    unsigned short* Vt     = (unsigned short*)(ws + 75497472);     // 16,777,216 B
    unsigned short* attnb  = (unsigned short*)(ws + 92274688);     // 16,777,216 B

    prep<<<6144, 256, 0, stream>>>(X, Xb, Wqkv, WqkvT, Wproj, WprojT);
    gemm_bf16<true, true, 3><<<(3072 / BN) * (8192 / BM), 256, 0, stream>>>(
        Xb, WqkvT, bqkv, qkvb, Vt, 8192, 3072, 1024);
    attention<<<1024, 128, 0, stream>>>(qkvb, Vt, attnb);
    gemm_bf16<false, false, 1><<<(1024 / BN) * (8192 / BM), 256, 0, stream>>>(
        attnb, WprojT, bproj, out, nullptr, 8192, 1024, 1024);
}

// Round 12
// 276.441 us; speedup vs baseline: 1.0408x; 1.0408x over previous
//
#include <hip/hip_runtime.h>
#include <hip/hip_bf16.h>

#define EMB 1024
#define SEQ 2048
#define ATT_SCALE 0.18033688011112042f  // 0.125 * log2(e)

typedef __bf16 bf16x8 __attribute__((ext_vector_type(8)));
typedef float f32x4 __attribute__((ext_vector_type(4)));
typedef float f32x16 __attribute__((ext_vector_type(16)));

__device__ __forceinline__ unsigned short f2bf(float f) {
    union { float f; unsigned int u; } v; v.f = f;
    unsigned int r = (v.u + 0x7FFFu + ((v.u >> 16) & 1u)) >> 16;
    return (unsigned short)r;
}

__device__ __forceinline__ void async_load16(const void* g, void* l) {
    __builtin_amdgcn_global_load_lds(
        (const __attribute__((address_space(1))) unsigned int*)g,
        (__attribute__((address_space(3))) unsigned int*)l, 16, 0, 0);
}

// ---------------- fused prep: X f32->bf16  +  Wqkv^T  +  Wproj^T ----------------
__global__ __launch_bounds__(256)
void prep(const float* __restrict__ X, unsigned short* __restrict__ Xb,
          const float* __restrict__ Wqkv, unsigned short* __restrict__ WqkvT,
          const float* __restrict__ Wproj, unsigned short* __restrict__ WprojT) {
    __shared__ float tile[32][33];
    const int id = blockIdx.x;
    const int tid = threadIdx.x;
    if (id < 4096) {
        const float* in;
        unsigned short* out;
        int bx, by, C;
        if (id < 3072) { in = Wqkv; out = WqkvT; C = 3072; bx = (id % 96) * 32; by = (id / 96) * 32; }
        else           { int t = id - 3072; in = Wproj; out = WprojT; C = 1024; bx = (t % 32) * 32; by = (t / 32) * 32; }
        int tx = tid & 31;
        int ty = tid >> 5;
        #pragma unroll
        for (int i = 0; i < 32; i += 8)
            tile[ty + i][tx] = in[(size_t)(by + ty + i) * C + bx + tx];
        __syncthreads();
        #pragma unroll
        for (int i = 0; i < 32; i += 8)
            out[(size_t)(bx + ty + i) * 1024 + by + tx] = f2bf(tile[tx][ty + i]);
    } else {
        const int n4 = (4 * 2048 * 1024) / 4;
        int i = (id - 4096) * 256 + tid;
        const int stride = 2048 * 256;
        const float4* inv = (const float4*)X;
        ushort4* outv = (ushort4*)Xb;
        for (; i < n4; i += stride) {
            float4 v = inv[i];
            ushort4 o;
            o.x = f2bf(v.x); o.y = f2bf(v.y); o.z = f2bf(v.z); o.w = f2bf(v.w);
            outv[i] = o;
        }
    }
}

// ---------------- 8-phase 256x256 QKV GEMM (T2+T3+T4+T5) ----------------
// C = A(8192x1024) * Bt(3072x1024)^T + bias; bf16 out; V cols written
// transposed to Vt; Q cols pre-scaled by ATT_SCALE.
// 512 thr = 8 waves (2M x 4N), 128x64 out/wave, BK=64. LDS 128 KB: even
// K-tiles in As0/Bs0, odd in As1/Bs1. Per phase: ds_read A-quadrant (+8
// B-frags at tile start) | stage 1 half-tile | barrier | lgkmcnt(0) |
// 8 MFMA (setprio) | barrier. Stage order follows consumption: p0/p1 A(t+1),
// p2/p3 B(t+2), p4/p5 A(t+2), p6/p7 B(t+3). vmcnt(4) ONLY at the two
// tile boundaries (next tile's 8 loads = oldest 8 of 12 in flight).
__global__ __launch_bounds__(512, 2)
void gemm256(const unsigned short* __restrict__ A,
             const unsigned short* __restrict__ Bt,
             const float* __restrict__ bias,
             unsigned short* __restrict__ Cout,
             unsigned short* __restrict__ Vtout,
             int M, int N, int K) {
    __shared__ unsigned short As0[256 * 64];
    __shared__ unsigned short As1[256 * 64];
    __shared__ unsigned short Bs0[256 * 64];
    __shared__ unsigned short Bs1[256 * 64];
    const int tid = threadIdx.x;
    const int lane = tid & 63;
    const int wave = tid >> 6;     // 0..7
    const int wr = wave >> 2;      // 0..1 (M)
    const int wc = wave & 3;       // 0..3 (N)
    const int l31 = lane & 31;
    const int half = lane >> 5;
    const int trow = tid >> 3;     // 0..63
    const int tch = tid & 7;

    // 384 blocks: xcd owns 4 contiguous m-panels (A panel 2MB L2-resident)
    const int id = blockIdx.x;
    const int xcd = id & 7;
    const int loc = id >> 3;               // 0..47
    const int m0 = (xcd * 4 + loc / 12) * 256;
    const int n0 = (loc % 12) * 256;

    f32x16 acc[4][2] = {};
    bf16x8 bfr[2][4];

    auto stageHalf = [&](unsigned short* dst, const unsigned short* src,
                         int srcRow0, int tile, int hb) {
        #pragma unroll
        for (int j = 0; j < 2; j++) {
            int rloc = hb * 128 + trow + 64 * j;
            int lc = tch ^ (rloc & 7);
            async_load16(&src[(size_t)(srcRow0 + rloc) * K + tile * 64 + lc * 8],
                         &dst[(hb * 128 + (wave << 3) + 64 * j) * 64]);
        }
    };
    auto loadB = [&](const unsigned short* Bb) {
        #pragma unroll
        for (int nt = 0; nt < 2; nt++) {
            int rb = wc * 64 + nt * 32 + l31;
            #pragma unroll
            for (int ks = 0; ks < 4; ks++)
                bfr[nt][ks] = *(const bf16x8*)&Bb[rb * 64 + (((ks * 2 + half)) ^ (rb & 7)) * 8];
        }
    };
    // phase: lb: reload B-frags; vm: -1 none, 4/0 counted drain before barrier2
    auto runPhase = [&](const unsigned short* Ab, const unsigned short* Bb,
                        int q, bool lb, auto&& stage, int vm) {
        if (lb) loadB(Bb);
        const int ra = wr * 128 + q * 32 + l31;
        bf16x8 af[4];
        #pragma unroll
        for (int ks = 0; ks < 4; ks++)
            af[ks] = *(const bf16x8*)&Ab[ra * 64 + (((ks * 2 + half)) ^ (ra & 7)) * 8];
        stage();
        __builtin_amdgcn_s_barrier();
        asm volatile("s_waitcnt lgkmcnt(0)" ::: "memory");
        __builtin_amdgcn_sched_barrier(0);
        __builtin_amdgcn_s_setprio(1);
        #pragma unroll
        for (int nt = 0; nt < 2; nt++)
            #pragma unroll
            for (int ks = 0; ks < 4; ks++)
                acc[q][nt] = __builtin_amdgcn_mfma_f32_32x32x16_bf16(
                    af[ks], bfr[nt][ks], acc[q][nt], 0, 0, 0);
        __builtin_amdgcn_s_setprio(0);
        if (vm == 4)      asm volatile("s_waitcnt vmcnt(4)" ::: "memory");
        else if (vm == 0) asm volatile("s_waitcnt vmcnt(0)" ::: "memory");
        __builtin_amdgcn_s_barrier();
        __builtin_amdgcn_sched_barrier(0);
    };
    auto nop = [&] {};

    // prologue: A0, B0, B1 staged; wait tile 0 (oldest 8), B1 stays in flight
    stageHalf(As0, A, m0, 0, 0);
    stageHalf(As0, A, m0, 0, 1);
    stageHalf(Bs0, Bt, n0, 0, 0);
    stageHalf(Bs0, Bt, n0, 0, 1);
    stageHalf(Bs1, Bt, n0, 1, 0);
    stageHalf(Bs1, Bt, n0, 1, 1);
    asm volatile("s_waitcnt vmcnt(4)" ::: "memory");
    __builtin_amdgcn_s_barrier();
    __builtin_amdgcn_sched_barrier(0);

    for (int i = 0; i < 7; i++) {
        const int t1 = 2 * i + 1;
        // tile 2i from buf0
        runPhase(As0, Bs0, 0, true,  [&] { stageHalf(As1, A,  m0, t1, 0); }, -1);
        runPhase(As0, Bs0, 1, false, [&] { stageHalf(As1, A,  m0, t1, 1); }, -1);
        runPhase(As0, Bs0, 2, false, [&] { stageHalf(Bs0, Bt, n0, t1 + 1, 0); }, -1);
        runPhase(As0, Bs0, 3, false, [&] { stageHalf(Bs0, Bt, n0, t1 + 1, 1); }, 4);
        // tile 2i+1 from buf1
        runPhase(As1, Bs1, 0, true,  [&] { stageHalf(As0, A,  m0, t1 + 1, 0); }, -1);
        runPhase(As1, Bs1, 1, false, [&] { stageHalf(As0, A,  m0, t1 + 1, 1); }, -1);
        runPhase(As1, Bs1, 2, false, [&] { stageHalf(Bs1, Bt, n0, t1 + 2, 0); }, -1);
        runPhase(As1, Bs1, 3, false, [&] { stageHalf(Bs1, Bt, n0, t1 + 2, 1); }, 4);
    }
    // peeled last iteration: tiles 14 (buf0), 15 (buf1); only A15 left to stage
    runPhase(As0, Bs0, 0, true,  [&] { stageHalf(As1, A, m0, 15, 0); }, -1);
    runPhase(As0, Bs0, 1, false, [&] { stageHalf(As1, A, m0, 15, 1); }, -1);
    runPhase(As0, Bs0, 2, false, nop, -1);
    runPhase(As0, Bs0, 3, false, nop, 0);
    runPhase(As1, Bs1, 0, true,  nop, -1);
    runPhase(As1, Bs1, 1, false, nop, -1);
    runPhase(As1, Bs1, 2, false, nop, -1);
    runPhase(As1, Bs1, 3, false, nop, -1);

    // epilogue: bias + Vt-fuse (col>=2048) + Q pre-scale (col<1024)
    #pragma unroll
    for (int q = 0; q < 4; q++) {
        #pragma unroll
        for (int nt = 0; nt < 2; nt++) {
            int col = n0 + wc * 64 + nt * 32 + l31;
            float bv = bias[col];
            if (col >= 2 * EMB) {
                int dd = col - 2 * EMB;
                #pragma unroll
                for (int g = 0; g < 4; g++) {
                    int row0 = m0 + wr * 128 + q * 32 + 8 * g + 4 * half;
                    int b = row0 >> 11;
                    int s = row0 & 2047;
                    ushort4 o;
                    o.x = f2bf(acc[q][nt][4 * g + 0] + bv);
                    o.y = f2bf(acc[q][nt][4 * g + 1] + bv);
                    o.z = f2bf(acc[q][nt][4 * g + 2] + bv);
                    o.w = f2bf(acc[q][nt][4 * g + 3] + bv);
                    *(ushort4*)&Vtout[((size_t)(b * 16) * 64 + dd) * SEQ + s] = o;
                }
            } else {
                const bool qs = col < EMB;
                #pragma unroll
                for (int reg = 0; reg < 16; reg++) {
                    int row = m0 + wr * 128 + q * 32 + (reg & 3) + 8 * (reg >> 2) + 4 * half;
                    float val = acc[q][nt][reg] + bv;
                    if (qs) val *= ATT_SCALE;
                    Cout[(size_t)row * N + col] = f2bf(val);
                }
            }
        }
    }
}

// ---------------- bf16 MFMA GEMM 128x128 (proj path, proven) ----------------
#define BM 128
#define BN 128
#define BK 64

template<bool OUT_BF16, int NPER>
__global__ __launch_bounds__(256, 4)
void gemm_bf16(const unsigned short* __restrict__ A,
               const unsigned short* __restrict__ Bt,
               const float* __restrict__ bias,
               void* __restrict__ Cout,
               int M, int N, int K) {
    __shared__ unsigned short As[BM * 64];
    __shared__ unsigned short Bs[BN * 64];
    const int tid = threadIdx.x;
    const int id = blockIdx.x;
    const int xcd = id & 7;
    const int loc = id >> 3;
    const int m0 = (loc / NPER) * BM;
    const int n0 = (xcd * NPER + (loc % NPER)) * BN;
    const int lane = tid & 63;
    const int wave = tid >> 6;
    const int wm = (wave & 1) * 64;
    const int wn = (wave >> 1) * 64;
    const int l31 = lane & 31;
    const int half = lane >> 5;
    const int r8 = lane >> 3;
    const int pc = lane & 7;

    const int srow = wave * 32 + r8;
    f32x16 acc[2][2] = {};

    for (int k0 = 0; k0 < K; k0 += BK) {
        __syncthreads();
        #pragma unroll
        for (int i = 0; i < 4; i++) {
            int r = srow + i * 8;
            int lc = pc ^ (r & 7);
            async_load16(&A[(size_t)(m0 + r) * K + k0 + lc * 8], &As[(wave * 32 + i * 8) * 64]);
            async_load16(&Bt[(size_t)(n0 + r) * K + k0 + lc * 8], &Bs[(wave * 32 + i * 8) * 64]);
        }
        __syncthreads();
        #pragma unroll
        for (int ks = 0; ks < 4; ks++) {
            const int lch = ks * 2 + half;
            bf16x8 af[2], bf[2];
            #pragma unroll
            for (int t = 0; t < 2; t++) {
                int ra = wm + t * 32 + l31;
                int rb = wn + t * 32 + l31;
                af[t] = *(const bf16x8*)&As[ra * 64 + (lch ^ (ra & 7)) * 8];
                bf[t] = *(const bf16x8*)&Bs[rb * 64 + (lch ^ (rb & 7)) * 8];
            }
            #pragma unroll
            for (int mt = 0; mt < 2; mt++)
                #pragma unroll
                for (int nt = 0; nt < 2; nt++)
                    acc[mt][nt] = __builtin_amdgcn_mfma_f32_32x32x16_bf16(
                        af[mt], bf[nt], acc[mt][nt], 0, 0, 0);
        }
    }
    #pragma unroll
    for (int mt = 0; mt < 2; mt++) {
        #pragma unroll
        for (int nt = 0; nt < 2; nt++) {
            int col = n0 + wn + nt * 32 + l31;
            float bv = bias[col];
            #pragma unroll
            for (int reg = 0; reg < 16; reg++) {
                int row = m0 + wm + mt * 32 + (reg & 3) + 8 * (reg >> 2) + 4 * half;
                float val = acc[mt][nt][reg] + bv;
                if (OUT_BF16)
                    ((unsigned short*)Cout)[(size_t)row * N + col] = f2bf(val);
                else
                    ((float*)Cout)[(size_t)row * N + col] = val;
            }
        }
    }
}

// ---------------- MFMA flash attention, S^T (R5/R9 proven 4-wave) ----------------
__global__ __launch_bounds__(256, 4)
void attention(const unsigned short* __restrict__ qkv,   // [8192][3072] bf16
               const unsigned short* __restrict__ vt,    // [64][64][2048] bf16
               unsigned short* __restrict__ outb) {      // [8192][1024] bf16
    __shared__ unsigned short smem[2 * 2 * 64 * 64];     // 32 KB
    const int tid = threadIdx.x;
    const int lane = tid & 63;
    const int wave = tid >> 6;
    const int l31 = lane & 31;
    const int half = lane >> 5;

    const int id = blockIdx.x;
    const int m4 = ((id >> 8) << 2) | (id & 3);
    const int qt = (int)((0xF12C4A97865B3DE0ULL >> (m4 * 4)) & 15);
    const int bh = (id & 255) >> 2;
    const int b = bh >> 4;
    const int h = bh & 15;

    const int qs = qt * 128 + wave * 32 + l31;
    const size_t qgrow = (size_t)b * SEQ + qs;

    bf16x8 qf[4];
    #pragma unroll
    for (int dt = 0; dt < 4; dt++)
        qf[dt] = *(const bf16x8*)&qkv[qgrow * 3072 + h * 64 + dt * 16 + half * 8];

    f32x16 o[2] = {};
    float tsum[8];
    #pragma unroll
    for (int r = 0; r < 8; r++) tsum[r] = 0.f;

    const int nkb = 2 * qt + 2;
    const int qmax_w = qt * 128 + wave * 32 + 31;

    const int row8 = lane >> 3;
    const int chsw = ((lane & 7) ^ row8) * 8;

    #pragma unroll
    for (int i = 0; i < 2; i++) {
        int row = wave * 16 + i * 8 + row8;
        async_load16(&qkv[(size_t)(b * SEQ + row) * 3072 + EMB + h * 64 + chsw],
                     &smem[(wave * 16 + i * 8) * 64]);
        async_load16(&vt[(size_t)(bh * 64 + row) * SEQ + chsw],
                     &smem[4096 + (wave * 16 + i * 8) * 64]);
    }

    for (int kb = 0; kb < nkb; kb++) {
        unsigned short* Ks = smem + (kb & 1) * 8192;
        unsigned short* Vs = Ks + 4096;
        __syncthreads();
        if (kb + 1 < nkb) {
            unsigned short* nb = smem + ((kb + 1) & 1) * 8192;
            #pragma unroll
            for (int i = 0; i < 2; i++) {
                int row = wave * 16 + i * 8 + row8;
                async_load16(&qkv[(size_t)(b * SEQ + (kb + 1) * 64 + row) * 3072 + EMB + h * 64 + chsw],
                             &nb[(wave * 16 + i * 8) * 64]);
                async_load16(&vt[(size_t)(bh * 64 + row) * SEQ + (kb + 1) * 64 + chsw],
                             &nb[4096 + (wave * 16 + i * 8) * 64]);
            }
        }
        if (kb * 64 > qmax_w) continue;

        f32x16 st[2] = {};
        __builtin_amdgcn_s_setprio(1);
        #pragma unroll
        for (int dt = 0; dt < 4; dt++) {
            #pragma unroll
            for (int ct = 0; ct < 2; ct++) {
                int kr = ct * 32 + l31;
                bf16x8 kf = *(const bf16x8*)&Ks[kr * 64 + ((dt * 2 + half) ^ (l31 & 7)) * 8];
                st[ct] = __builtin_amdgcn_mfma_f32_32x32x16_bf16(kf, qf[dt], st[ct], 0, 0, 0);
            }
        }
        __builtin_amdgcn_s_setprio(0);

        if (kb * 64 + 63 > qt * 128 + wave * 32) {
            #pragma unroll
            for (int ct = 0; ct < 2; ct++)
                #pragma unroll
                for (int r = 0; r < 16; r++) {
                    int cg = kb * 64 + ct * 32 + (r & 3) + 8 * (r >> 2) + 4 * half;
                    if (cg > qs) st[ct][r] = -1e9f;
                }
        }

        #pragma unroll
        for (int r = 0; r < 16; r++) {
            st[0][r] = exp2f(st[0][r]);
            st[1][r] = exp2f(st[1][r]);
        }
        #pragma unroll
        for (int r = 0; r < 8; r++)
            tsum[r] += (st[0][r] + st[1][r]) + (st[0][r + 8] + st[1][r + 8]);

        unsigned int pk[2][8];
        #pragma unroll
        for (int t = 0; t < 2; t++)
            #pragma unroll
            for (int i = 0; i < 8; i++) {
                __hip_bfloat162 pb = __float22bfloat162_rn(float2{st[t][2 * i], st[t][2 * i + 1]});
                union { __hip_bfloat162 b; unsigned int u; } cv; cv.b = pb;
                pk[t][i] = cv.u;
            }

        __builtin_amdgcn_s_setprio(1);
        #pragma unroll
        for (int kt = 0; kt < 4; kt++) {
            const int t = kt >> 1, e = kt & 1;
            unsigned int a0 = pk[t][4 * e + 0], b0 = pk[t][4 * e + 2];
            unsigned int a1 = pk[t][4 * e + 1], b1 = pk[t][4 * e + 3];
            asm("v_permlane32_swap_b32 %0, %1" : "+v"(a0), "+v"(b0));
            asm("v_permlane32_swap_b32 %0, %1" : "+v"(a1), "+v"(b1));
            union { uint4 u; bf16x8 v; } pf;
            pf.u.x = a0; pf.u.y = a1; pf.u.z = b0; pf.u.w = b1;
            #pragma unroll
            for (int dt = 0; dt < 2; dt++) {
                int vr = dt * 32 + l31;
                bf16x8 vf = *(const bf16x8*)&Vs[vr * 64 + ((kt * 2 + half) ^ (l31 & 7)) * 8];
                o[dt] = __builtin_amdgcn_mfma_f32_32x32x16_bf16(vf, pf.v, o[dt], 0, 0, 0);
            }
        }
        __builtin_amdgcn_s_setprio(0);
    }

    __syncthreads();
    #pragma unroll
    for (int s = 4; s > 0; s >>= 1)
        #pragma unroll
        for (int r = 0; r < s; r++) tsum[r] += tsum[r + s];
    float lt = tsum[0] + __shfl_xor(tsum[0], 32, 64);
    float inv = 1.0f / lt;
    #pragma unroll
    for (int dt = 0; dt < 2; dt++)
        #pragma unroll
        for (int r = 0; r < 16; r++) {
            int d = dt * 32 + (r & 3) + 8 * (r >> 2) + 4 * half;
            smem[(wave * 32 + l31) * 72 + d] = f2bf(o[dt][r] * inv);
        }
    __syncthreads();
    #pragma unroll
    for (int i = 0; i < 4; i++) {
        int c = tid + 256 * i;
        int row = c >> 3;
        int ch = (c & 7) * 8;
        uint4 v = *(const uint4*)&smem[row * 72 + ch];
        *(uint4*)&outb[(size_t)(b * SEQ + qt * 128 + row) * EMB + h * 64 + ch] = v;
    }
}

extern "C" void kernel_launch(void* const* d_in, const int* in_sizes, int n_in,
                              void* d_out, int out_size, void* d_ws, size_t ws_size,
                              hipStream_t stream) {
    const float* X     = (const float*)d_in[0];
    const float* Wqkv  = (const float*)d_in[1];
    const float* bqkv  = (const float*)d_in[2];
    const float* Wproj = (const float*)d_in[3];
    const float* bproj = (const float*)d_in[4];
    float* out = (float*)d_out;

    char* ws = (char*)d_ws;
    unsigned short* Xb     = (unsigned short*)(ws);                // 16,777,216 B
    unsigned short* WqkvT  = (unsigned short*)(ws + 16777216);     //  6,291,456 B
    unsigned short* WprojT = (unsigned short*)(ws + 23068672);     //  2,097,152 B
    unsigned short* qkvb   = (unsigned short*)(ws + 25165824);     // 50,331,648 B
    unsigned short* Vt     = (unsigned short*)(ws + 75497472);     // 16,777,216 B
    unsigned short* attnb  = (unsigned short*)(ws + 92274688);     // 16,777,216 B

    prep<<<6144, 256, 0, stream>>>(X, Xb, Wqkv, WqkvT, Wproj, WprojT);
    gemm256<<<384, 512, 0, stream>>>(Xb, WqkvT, bqkv, qkvb, Vt, 8192, 3072, 1024);
    attention<<<1024, 256, 0, stream>>>(qkvb, Vt, attnb);
    gemm_bf16<false, 1><<<(1024 / BN) * (8192 / BM), 256, 0, stream>>>(
        attnb, WprojT, bproj, out, 8192, 1024, 1024);
}

// Round 13
// 257.844 us; speedup vs baseline: 1.1159x; 1.0721x over previous
//
#include <hip/hip_runtime.h>
#include <hip/hip_bf16.h>

#define EMB 1024
#define SEQ 2048
#define ATT_SCALE 0.18033688011112042f  // 0.125 * log2(e)

typedef __bf16 bf16x8 __attribute__((ext_vector_type(8)));
typedef float f32x4 __attribute__((ext_vector_type(4)));
typedef float f32x16 __attribute__((ext_vector_type(16)));

__device__ __forceinline__ unsigned short f2bf(float f) {
    union { float f; unsigned int u; } v; v.f = f;
    unsigned int r = (v.u + 0x7FFFu + ((v.u >> 16) & 1u)) >> 16;
    return (unsigned short)r;
}

__device__ __forceinline__ void async_load16(const void* g, void* l) {
    __builtin_amdgcn_global_load_lds(
        (const __attribute__((address_space(1))) unsigned int*)g,
        (__attribute__((address_space(3))) unsigned int*)l, 16, 0, 0);
}

// ---------------- fused prep: X f32->bf16  +  Wqkv^T  +  Wproj^T ----------------
__global__ __launch_bounds__(256)
void prep(const float* __restrict__ X, unsigned short* __restrict__ Xb,
          const float* __restrict__ Wqkv, unsigned short* __restrict__ WqkvT,
          const float* __restrict__ Wproj, unsigned short* __restrict__ WprojT) {
    __shared__ float tile[32][33];
    const int id = blockIdx.x;
    const int tid = threadIdx.x;
    if (id < 4096) {
        const float* in;
        unsigned short* out;
        int bx, by, C;
        if (id < 3072) { in = Wqkv; out = WqkvT; C = 3072; bx = (id % 96) * 32; by = (id / 96) * 32; }
        else           { int t = id - 3072; in = Wproj; out = WprojT; C = 1024; bx = (t % 32) * 32; by = (t / 32) * 32; }
        int tx = tid & 31;
        int ty = tid >> 5;
        #pragma unroll
        for (int i = 0; i < 32; i += 8)
            tile[ty + i][tx] = in[(size_t)(by + ty + i) * C + bx + tx];
        __syncthreads();
        #pragma unroll
        for (int i = 0; i < 32; i += 8)
            out[(size_t)(bx + ty + i) * 1024 + by + tx] = f2bf(tile[tx][ty + i]);
    } else {
        const int n4 = (4 * 2048 * 1024) / 4;
        int i = (id - 4096) * 256 + tid;
        const int stride = 2048 * 256;
        const float4* inv = (const float4*)X;
        ushort4* outv = (ushort4*)Xb;
        for (; i < n4; i += stride) {
            float4 v = inv[i];
            ushort4 o;
            o.x = f2bf(v.x); o.y = f2bf(v.y); o.z = f2bf(v.z); o.w = f2bf(v.w);
            outv[i] = o;
        }
    }
}

// ---------------- bf16 MFMA GEMM, 32x32x16: C[M,N] = A * Bt^T + bias ----------------
// R5/R8-proven single-buffer 2-barrier structure (plateau config: R5-R12 showed
// dbuf / counted-vmcnt / occupancy / 8-phase-256^2 all null or worse).
// CS = C row stride (QKV writes only Q,K cols -> compact stride 2048).
// FUSE_VT pre-scales Q cols (col < EMB) by ATT_SCALE and writes V cols
// transposed to Vtout.
#define BM 128
#define BN 128
#define BK 64

template<bool OUT_BF16, bool FUSE_VT, int NPER>
__global__ __launch_bounds__(256, 4)
void gemm_bf16(const unsigned short* __restrict__ A,
               const unsigned short* __restrict__ Bt,
               const float* __restrict__ bias,
               void* __restrict__ Cout,
               unsigned short* __restrict__ Vtout,
               int M, int N, int K, int CS) {
    __shared__ unsigned short As[BM * 64];
    __shared__ unsigned short Bs[BN * 64];
    const int tid = threadIdx.x;
    const int id = blockIdx.x;
    const int xcd = id & 7;
    const int loc = id >> 3;
    const int m0 = (loc / NPER) * BM;
    const int n0 = (xcd * NPER + (loc % NPER)) * BN;
    const int lane = tid & 63;
    const int wave = tid >> 6;
    const int wm = (wave & 1) * 64;
    const int wn = (wave >> 1) * 64;
    const int l31 = lane & 31;
    const int half = lane >> 5;
    const int r8 = lane >> 3;
    const int pc = lane & 7;

    const int srow = wave * 32 + r8;
    f32x16 acc[2][2] = {};

    for (int k0 = 0; k0 < K; k0 += BK) {
        __syncthreads();
        #pragma unroll
        for (int i = 0; i < 4; i++) {
            int r = srow + i * 8;
            int lc = pc ^ (r & 7);
            async_load16(&A[(size_t)(m0 + r) * K + k0 + lc * 8], &As[(wave * 32 + i * 8) * 64]);
            async_load16(&Bt[(size_t)(n0 + r) * K + k0 + lc * 8], &Bs[(wave * 32 + i * 8) * 64]);
        }
        __syncthreads();
        #pragma unroll
        for (int ks = 0; ks < 4; ks++) {
            const int lch = ks * 2 + half;
            bf16x8 af[2], bf[2];
            #pragma unroll
            for (int t = 0; t < 2; t++) {
                int ra = wm + t * 32 + l31;
                int rb = wn + t * 32 + l31;
                af[t] = *(const bf16x8*)&As[ra * 64 + (lch ^ (ra & 7)) * 8];
                bf[t] = *(const bf16x8*)&Bs[rb * 64 + (lch ^ (rb & 7)) * 8];
            }
            #pragma unroll
            for (int mt = 0; mt < 2; mt++)
                #pragma unroll
                for (int nt = 0; nt < 2; nt++)
                    acc[mt][nt] = __builtin_amdgcn_mfma_f32_32x32x16_bf16(
                        af[mt], bf[nt], acc[mt][nt], 0, 0, 0);
        }
    }
    #pragma unroll
    for (int mt = 0; mt < 2; mt++) {
        #pragma unroll
        for (int nt = 0; nt < 2; nt++) {
            int col = n0 + wn + nt * 32 + l31;
            float bv = bias[col];
            if (FUSE_VT && col >= 2 * EMB) {
                int dd = col - 2 * EMB;
                #pragma unroll
                for (int g = 0; g < 4; g++) {
                    int row0 = m0 + wm + mt * 32 + 8 * g + 4 * half;
                    int b = row0 >> 11;
                    int s = row0 & 2047;
                    ushort4 o;
                    o.x = f2bf(acc[mt][nt][4 * g + 0] + bv);
                    o.y = f2bf(acc[mt][nt][4 * g + 1] + bv);
                    o.z = f2bf(acc[mt][nt][4 * g + 2] + bv);
                    o.w = f2bf(acc[mt][nt][4 * g + 3] + bv);
                    *(ushort4*)&Vtout[((size_t)(b * 16) * 64 + dd) * SEQ + s] = o;
                }
            } else {
                const bool qscale = FUSE_VT && (col < EMB);
                #pragma unroll
                for (int reg = 0; reg < 16; reg++) {
                    int row = m0 + wm + mt * 32 + (reg & 3) + 8 * (reg >> 2) + 4 * half;
                    float val = acc[mt][nt][reg] + bv;
                    if (qscale) val *= ATT_SCALE;
                    if (OUT_BF16)
                        ((unsigned short*)Cout)[(size_t)row * CS + col] = f2bf(val);
                    else
                        ((float*)Cout)[(size_t)row * CS + col] = val;
                }
            }
        }
    }
}

// ---------------- MFMA flash attention, S^T (R5/R9 proven 4-wave) ----------------
// qk buffer is now stride-2048 (Q cols [0,1024), K cols [1024,2048)).
__global__ __launch_bounds__(256, 4)
void attention(const unsigned short* __restrict__ qk,    // [8192][2048] bf16
               const unsigned short* __restrict__ vt,    // [64][64][2048] bf16
               unsigned short* __restrict__ outb) {      // [8192][1024] bf16
    __shared__ unsigned short smem[2 * 2 * 64 * 64];     // 32 KB
    const int tid = threadIdx.x;
    const int lane = tid & 63;
    const int wave = tid >> 6;
    const int l31 = lane & 31;
    const int half = lane >> 5;

    const int id = blockIdx.x;
    const int m4 = ((id >> 8) << 2) | (id & 3);
    const int qt = (int)((0xF12C4A97865B3DE0ULL >> (m4 * 4)) & 15);
    const int bh = (id & 255) >> 2;
    const int b = bh >> 4;
    const int h = bh & 15;

    const int qs = qt * 128 + wave * 32 + l31;
    const size_t qgrow = (size_t)b * SEQ + qs;

    bf16x8 qf[4];
    #pragma unroll
    for (int dt = 0; dt < 4; dt++)
        qf[dt] = *(const bf16x8*)&qk[qgrow * 2048 + h * 64 + dt * 16 + half * 8];

    f32x16 o[2] = {};
    float tsum[8];
    #pragma unroll
    for (int r = 0; r < 8; r++) tsum[r] = 0.f;

    const int nkb = 2 * qt + 2;
    const int qmax_w = qt * 128 + wave * 32 + 31;

    const int row8 = lane >> 3;
    const int chsw = ((lane & 7) ^ row8) * 8;

    #pragma unroll
    for (int i = 0; i < 2; i++) {
        int row = wave * 16 + i * 8 + row8;
        async_load16(&qk[(size_t)(b * SEQ + row) * 2048 + EMB + h * 64 + chsw],
                     &smem[(wave * 16 + i * 8) * 64]);
        async_load16(&vt[(size_t)(bh * 64 + row) * SEQ + chsw],
                     &smem[4096 + (wave * 16 + i * 8) * 64]);
    }

    for (int kb = 0; kb < nkb; kb++) {
        unsigned short* Ks = smem + (kb & 1) * 8192;
        unsigned short* Vs = Ks + 4096;
        __syncthreads();
        if (kb + 1 < nkb) {
            unsigned short* nb = smem + ((kb + 1) & 1) * 8192;
            #pragma unroll
            for (int i = 0; i < 2; i++) {
                int row = wave * 16 + i * 8 + row8;
                async_load16(&qk[(size_t)(b * SEQ + (kb + 1) * 64 + row) * 2048 + EMB + h * 64 + chsw],
                             &nb[(wave * 16 + i * 8) * 64]);
                async_load16(&vt[(size_t)(bh * 64 + row) * SEQ + (kb + 1) * 64 + chsw],
                             &nb[4096 + (wave * 16 + i * 8) * 64]);
            }
        }
        if (kb * 64 > qmax_w) continue;

        f32x16 st[2] = {};
        __builtin_amdgcn_s_setprio(1);
        #pragma unroll
        for (int dt = 0; dt < 4; dt++) {
            #pragma unroll
            for (int ct = 0; ct < 2; ct++) {
                int kr = ct * 32 + l31;
                bf16x8 kf = *(const bf16x8*)&Ks[kr * 64 + ((dt * 2 + half) ^ (l31 & 7)) * 8];
                st[ct] = __builtin_amdgcn_mfma_f32_32x32x16_bf16(kf, qf[dt], st[ct], 0, 0, 0);
            }
        }
        __builtin_amdgcn_s_setprio(0);

        if (kb * 64 + 63 > qt * 128 + wave * 32) {
            #pragma unroll
            for (int ct = 0; ct < 2; ct++)
                #pragma unroll
                for (int r = 0; r < 16; r++) {
                    int cg = kb * 64 + ct * 32 + (r & 3) + 8 * (r >> 2) + 4 * half;
                    if (cg > qs) st[ct][r] = -1e9f;
                }
        }

        #pragma unroll
        for (int r = 0; r < 16; r++) {
            st[0][r] = exp2f(st[0][r]);
            st[1][r] = exp2f(st[1][r]);
        }
        #pragma unroll
        for (int r = 0; r < 8; r++)
            tsum[r] += (st[0][r] + st[1][r]) + (st[0][r + 8] + st[1][r + 8]);

        unsigned int pk[2][8];
        #pragma unroll
        for (int t = 0; t < 2; t++)
            #pragma unroll
            for (int i = 0; i < 8; i++) {
                __hip_bfloat162 pb = __float22bfloat162_rn(float2{st[t][2 * i], st[t][2 * i + 1]});
                union { __hip_bfloat162 b; unsigned int u; } cv; cv.b = pb;
                pk[t][i] = cv.u;
            }

        __builtin_amdgcn_s_setprio(1);
        #pragma unroll
        for (int kt = 0; kt < 4; kt++) {
            const int t = kt >> 1, e = kt & 1;
            unsigned int a0 = pk[t][4 * e + 0], b0 = pk[t][4 * e + 2];
            unsigned int a1 = pk[t][4 * e + 1], b1 = pk[t][4 * e + 3];
            asm("v_permlane32_swap_b32 %0, %1" : "+v"(a0), "+v"(b0));
            asm("v_permlane32_swap_b32 %0, %1" : "+v"(a1), "+v"(b1));
            union { uint4 u; bf16x8 v; } pf;
            pf.u.x = a0; pf.u.y = a1; pf.u.z = b0; pf.u.w = b1;
            #pragma unroll
            for (int dt = 0; dt < 2; dt++) {
                int vr = dt * 32 + l31;
                bf16x8 vf = *(const bf16x8*)&Vs[vr * 64 + ((kt * 2 + half) ^ (l31 & 7)) * 8];
                o[dt] = __builtin_amdgcn_mfma_f32_32x32x16_bf16(vf, pf.v, o[dt], 0, 0, 0);
            }
        }
        __builtin_amdgcn_s_setprio(0);
    }

    __syncthreads();
    #pragma unroll
    for (int s = 4; s > 0; s >>= 1)
        #pragma unroll
        for (int r = 0; r < s; r++) tsum[r] += tsum[r + s];
    float lt = tsum[0] + __shfl_xor(tsum[0], 32, 64);
    float inv = 1.0f / lt;
    #pragma unroll
    for (int dt = 0; dt < 2; dt++)
        #pragma unroll
        for (int r = 0; r < 16; r++) {
            int d = dt * 32 + (r & 3) + 8 * (r >> 2) + 4 * half;
            smem[(wave * 32 + l31) * 72 + d] = f2bf(o[dt][r] * inv);
        }
    __syncthreads();
    #pragma unroll
    for (int i = 0; i < 4; i++) {
        int c = tid + 256 * i;
        int row = c >> 3;
        int ch = (c & 7) * 8;
        uint4 v = *(const uint4*)&smem[row * 72 + ch];
        *(uint4*)&outb[(size_t)(b * SEQ + qt * 128 + row) * EMB + h * 64 + ch] = v;
    }
}

extern "C" void kernel_launch(void* const* d_in, const int* in_sizes, int n_in,
                              void* d_out, int out_size, void* d_ws, size_t ws_size,
                              hipStream_t stream) {
    const float* X     = (const float*)d_in[0];
    const float* Wqkv  = (const float*)d_in[1];
    const float* bqkv  = (const float*)d_in[2];
    const float* Wproj = (const float*)d_in[3];
    const float* bproj = (const float*)d_in[4];
    float* out = (float*)d_out;

    // Compact workspace (75.5 MB, was 104): qkvb stride 2048 (V never stored
    // there), attnb overlays Xb (dead after QKV GEMM).
    char* ws = (char*)d_ws;
    unsigned short* Xb     = (unsigned short*)(ws);                // 16,777,216 B (reused as attnb)
    unsigned short* WqkvT  = (unsigned short*)(ws + 16777216);     //  6,291,456 B
    unsigned short* WprojT = (unsigned short*)(ws + 23068672);     //  2,097,152 B
    unsigned short* qkb    = (unsigned short*)(ws + 25165824);     // 33,554,432 B  [8192][2048]
    unsigned short* Vt     = (unsigned short*)(ws + 58720256);     // 16,777,216 B
    unsigned short* attnb  = Xb;                                   // overlay

    prep<<<6144, 256, 0, stream>>>(X, Xb, Wqkv, WqkvT, Wproj, WprojT);
    gemm_bf16<true, true, 3><<<(3072 / BN) * (8192 / BM), 256, 0, stream>>>(
        Xb, WqkvT, bqkv, qkb, Vt, 8192, 3072, 1024, 2048);
    attention<<<1024, 256, 0, stream>>>(qkb, Vt, attnb);
    gemm_bf16<false, false, 1><<<(1024 / BN) * (8192 / BM), 256, 0, stream>>>(
        attnb, WprojT, bproj, out, nullptr, 8192, 1024, 1024, 1024);
}